// Round 10
// baseline (40217.593 us; speedup 1.0000x reference)
//
#include <hip/hip_runtime.h>
#include <hip/hip_bf16.h>
#include <hip/hip_fp16.h>
#include <math.h>

#define CS 96      // source len
#define CT 96      // target len
#define CE 256     // embed
#define CH 512     // hidden
#define CH2 1024
#define CH3 1536
#define CV 32000
#define CXD 1280   // E + 2H

typedef unsigned int u32;
typedef unsigned short u16;
typedef unsigned long long u64;

__device__ __forceinline__ float sigm(float x){ return 1.f/(1.f+expf(-x)); }

// packed-fp16 dot2 with fp32 accumulate
__device__ __forceinline__ float dot2f(u32 a, u32 b, float c){
#if __has_builtin(__builtin_amdgcn_fdot2)
  typedef _Float16 hv2 __attribute__((ext_vector_type(2)));
  hv2 x = __builtin_bit_cast(hv2, a), y = __builtin_bit_cast(hv2, b);
  return __builtin_amdgcn_fdot2(x, y, c, false);
#else
  __half2 x = __builtin_bit_cast(__half2, a), y = __builtin_bit_cast(__half2, b);
  return c + __half2float(x.x)*__half2float(y.x) + __half2float(x.y)*__half2float(y.y);
#endif
}

__device__ __forceinline__ u32 packh2(float a, float b){
  return (u32)__half_as_ushort(__float2half(a)) | ((u32)__half_as_ushort(__float2half(b)) << 16);
}

// lgkm-only barrier: drains LDS ops, NOT global stores (keeps store-ACK off the serial path)
#define COVBAR() do{ asm volatile("s_waitcnt lgkmcnt(0)" ::: "memory"); \
                     __builtin_amdgcn_sched_barrier(0); \
                     __builtin_amdgcn_s_barrier(); \
                     __builtin_amdgcn_sched_barrier(0); }while(0)

// ---------------- init: exchange slots + cov_last ----------------
__global__ void k_init(u32* hx, float* cov_last){
  int i = threadIdx.x;
  for (int j = i; j < 1024; j += 256) hx[j] = 0u;   // hc[2][256] u64 -> 1024 u32, tag=0
  for (int j = i; j < CH; j += 256) cov_last[j] = 0.f;
}

// ---------------- embedding gathers ----------------
__global__ void k_embed(const int* iseq, const int* oseq, const float* ee, const float* de,
                        float* x_enc, float* x_dec){
  int s = blockIdx.x, d = threadIdx.x;
  x_enc[s*CE+d] = ee[(long)iseq[s]*CE + d];
  x_dec[s*CE+d] = de[(long)oseq[s]*CE + d];
}

// ---------------- encoder input-gate precompute ----------------
__global__ void k_gi(const float* Wf, const float* bf, const float* Wb, const float* bb,
                     const float* x_enc, float* gf, float* gb){
  int idx = blockIdx.x*256 + threadIdx.x;
  int dir = idx / (CS*CH3);
  int rem = idx - dir*(CS*CH3);
  int s = rem / CH3, r = rem - s*CH3;
  const float* W = dir ? Wb : Wf;
  const float* b = dir ? bb : bf;
  const float* x = x_enc + s*CE;
  const float* w = W + (long)r*CE;
  float acc = b[r];
  #pragma unroll 8
  for (int k=0;k<CE;k++) acc += w[k]*x[k];
  (dir ? gb : gf)[s*CH3 + r] = acc;
}

// ---------------- one encoder step ----------------
__global__ void k_enc_step(int s, const float* Whf, const float* bhf, const float* Whb, const float* bhb,
                           const float* gf, const float* gb, float* outf, float* outb){
  int wg = blockIdx.x;
  int dir = wg >> 3;
  int jb = (wg & 7)*64;
  int t = threadIdx.x;
  int j = jb + (t>>2);
  int c0 = (t&3)*128;
  const float* Whh = dir ? Whb : Whf;
  const float* bhh = dir ? bhb : bhf;
  const float* gi  = dir ? gb : gf;
  float* o = dir ? outb : outf;
  int pos = dir ? (CS-1-s) : s;
  const float* hp = (s>0) ? (o + (dir ? (pos+1)*CH : (s-1)*CH)) : nullptr;
  float ar=0.f, az=0.f, an=0.f;
  if (s > 0){
    const float* wr = Whh + (long)j*CH;
    const float* wz = Whh + (long)(j+CH)*CH;
    const float* wn = Whh + (long)(j+2*CH)*CH;
    #pragma unroll 4
    for (int k=c0;k<c0+128;k++){
      float h = hp[k];
      ar += wr[k]*h; az += wz[k]*h; an += wn[k]*h;
    }
  }
  ar += __shfl_xor(ar,1); ar += __shfl_xor(ar,2);
  az += __shfl_xor(az,1); az += __shfl_xor(az,2);
  an += __shfl_xor(an,1); an += __shfl_xor(an,2);
  if ((t&3)==0){
    const float* g = gi + pos*CH3;
    float hpj = (s>0) ? hp[j] : 0.f;
    float r = sigm(g[j]       + ar + bhh[j]);
    float z = sigm(g[j+CH]    + az + bhh[j+CH]);
    float n = tanhf(g[j+2*CH] + r*(an + bhh[j+2*CH]));
    o[pos*CH + j] = (1.f-z)*n + z*hpj;
  }
}

// ---------------- ua_enc / Aenc precompute + h_carry init ----------------
__global__ void k_prep2(const float* ua, const float* Wic, const float* outf, const float* outb,
                        float* ua_enc, float* Aenc, float* h_carry){
  int idx = blockIdx.x*256 + threadIdx.x;
  if (idx < 2*CS*CH){
    int which = idx / (CS*CH);
    int rem = idx - which*(CS*CH);
    int s = rem / CH, r = rem - s*CH;
    const float* of = outf + s*CH;
    const float* ob = outb + s*CH;
    const float* w = which ? (Wic + (long)r*CH3) : (ua + (long)r*CH2);
    float acc = 0.f;
    #pragma unroll 4
    for (int k=0;k<CH;k++) acc += w[k]*of[k];
    #pragma unroll 4
    for (int k=0;k<CH;k++) acc += w[CH+k]*ob[k];
    (which ? Aenc : ua_enc)[s*CH + r] = acc;
  } else if (idx < 2*CS*CH + CH){
    int j = idx - 2*CS*CH;
    h_carry[j] = outf[(CS-1)*CH + j];
  }
}

// ---------------- fp32 -> bf16 (RNE) for lin_W ----------------
__global__ void k_cvt(const float* w, u16* o, int n){
  int i = blockIdx.x*blockDim.x + threadIdx.x;
  int stride = gridDim.x*blockDim.x;
  for (; i<n; i+=stride){
    union { float f; u32 u; } v; v.f = w[i];
    u32 r = (v.u + 0x7fffu + ((v.u>>16)&1u)) >> 16;
    o[i] = (u16)r;
  }
}

// ---------------- fp32 -> fp16 for coverage weights ----------------
__global__ void k_cvt_cov(const float* Whc, const float* Wic, u16* whc16, u16* wic16){
  int i = blockIdx.x*256 + threadIdx.x;     // 0 .. 2*CH*CH
  if (i < CH*CH){
    whc16[i] = __half_as_ushort(__float2half(Whc[i]));
  } else {
    int j = i - CH*CH;
    int r = j >> 9, c = j & 511;
    wic16[j] = __half_as_ushort(__float2half(Wic[(long)r*CH3 + CH2 + c]));
  }
}

// ---------------- wah = wa @ h (pre-loop only) ----------------
__global__ void k_wah(const float* wa, const float* h, float* wah){
  int j = blockIdx.x*64 + (threadIdx.x>>2);
  int c0 = (threadIdx.x&3)*128;
  const float* w = wa + (long)j*CH;
  float acc = 0.f;
  #pragma unroll 4
  for (int k=c0;k<c0+128;k++) acc += w[k]*h[k];
  acc += __shfl_xor(acc,1); acc += __shfl_xor(acc,2);
  if ((threadIdx.x&3)==0) wah[j] = acc;
}

// ---------------- attention scores e[s] ----------------
__global__ void k_attn(int t, const float* vc, const float* va,
                       const float* ua_enc, const float* cov_vec, const float* wah, float* e){
  int s = blockIdx.x, tid = threadIdx.x;
  __shared__ float red[4];
  float sum = 0.f;
  #pragma unroll
  for (int jj=0;jj<2;jj++){
    int j = tid + jj*256;
    float acc = ua_enc[s*CH + j] + wah[j];
    if (t > 0){
      const float* v = vc + (long)j*CH;
      const float* cvs = cov_vec + s*CH;
      #pragma unroll 4
      for (int k=0;k<CH;k++) acc += v[k]*cvs[k];
    }
    sum += va[j]*tanhf(acc);
  }
  for (int m=1;m<64;m<<=1) sum += __shfl_xor(sum,m);
  if ((tid&63)==0) red[tid>>6] = sum;
  __syncthreads();
  if (tid==0) e[s] = red[0]+red[1]+red[2]+red[3];
}

// ---------------- softmax + context ----------------
__global__ void k_soft(const float* e, const float* outf, const float* outb, float* alpha, float* ctx){
  int tid = threadIdx.x; // 128
  __shared__ float al[CS];
  __shared__ float rmax[2], rsum[2];
  float v = (tid<CS) ? e[tid] : -1e30f;
  float m = v;
  for (int k=1;k<64;k<<=1) m = fmaxf(m, __shfl_xor(m,k));
  if ((tid&63)==0) rmax[tid>>6] = m;
  __syncthreads();
  float gm = fmaxf(rmax[0], rmax[1]);
  float ex = (tid<CS) ? expf(v-gm) : 0.f;
  float sm2 = ex;
  for (int k=1;k<64;k<<=1) sm2 += __shfl_xor(sm2,k);
  if ((tid&63)==0) rsum[tid>>6] = sm2;
  __syncthreads();
  float inv = 1.f/(rsum[0]+rsum[1]);
  if (tid<CS){ float a = ex*inv; al[tid] = a; alpha[tid] = a; }
  __syncthreads();
  #pragma unroll
  for (int k=0;k<8;k++){
    int d = k*128 + tid;
    const float* src = (d<CH) ? outf : outb;
    int dd = (d<CH) ? d : d-CH;
    float acc = 0.f;
    for (int s2=0;s2<CS;s2++) acc += al[s2]*src[s2*CH+dd];
    ctx[d] = acc;
  }
}

// ---------------- decoder GRU ----------------
__global__ void k_gru(int t, const float* Wi, const float* bi, const float* Wh, const float* bh,
                      const float* ctx, const float* x_dec, const float* h_carry, float* h_cur){
  int wg = blockIdx.x, tid = threadIdx.x;
  int j = wg*8 + (tid>>5);
  int ln = tid&31;
  const float* xd = x_dec + t*CE;
  float ar=0.f, az=0.f, an=0.f;
  {
    int c0 = ln*40;
    const float* wr = Wi + (long)j*CXD;
    const float* wz = Wi + (long)(j+CH)*CXD;
    const float* wn = Wi + (long)(j+2*CH)*CXD;
    for (int k=c0;k<c0+40;k++){
      float x = (k<CH2) ? ctx[k] : xd[k-CH2];
      ar += wr[k]*x; az += wz[k]*x; an += wn[k]*x;
    }
  }
  float hr=0.f, hz=0.f, hn2=0.f;
  {
    int c0 = ln*16;
    const float* wr = Wh + (long)j*CH;
    const float* wz = Wh + (long)(j+CH)*CH;
    const float* wn = Wh + (long)(j+2*CH)*CH;
    for (int k=c0;k<c0+16;k++){
      float hv = h_carry[k];
      hr += wr[k]*hv; hz += wz[k]*hv; hn2 += wn[k]*hv;
    }
  }
  for (int m=1;m<32;m<<=1){
    ar+=__shfl_xor(ar,m); az+=__shfl_xor(az,m); an+=__shfl_xor(an,m);
    hr+=__shfl_xor(hr,m); hz+=__shfl_xor(hz,m); hn2+=__shfl_xor(hn2,m);
  }
  if (ln==0){
    float hprev = h_carry[j];
    float r = sigm(ar + bi[j]       + hr + bh[j]);
    float z = sigm(az + bi[j+CH]    + hz + bh[j+CH]);
    float n = tanhf(an + bi[j+2*CH] + r*(hn2 + bh[j+2*CH]));
    h_cur[j] = (1.f-z)*n + z*hprev;
  }
}

// ---------------- fused tail: blocks 0,1 coverage | 2,3 wah | 4..53 logits ----------------
// cov: 2 WGs x 256 rows, fence-free tagged u64 exchange (proven protocol), 256 pollers total.
template<int BF16>
__launch_bounds__(1024)
__global__ void k_tail(int t, const void* Wv, const float* lb, const float* h_cur, const float* ctx,
                       float* out, const float* wa, float* wah,
                       const u16* whc16, const u16* wic16, const float* bic, const float* bhc,
                       const float* Aenc, const float* alpha,
                       float* cov_vec, float* cov_last, u64* hc, float* h_carry){
  int b = blockIdx.x, tid = threadIdx.x;

  if (b >= 4){
    // ---- logits: 50 blocks x 16 waves = 800 row-walkers ----
    int ln = tid&63;
    int gw = (b-4)*16 + (tid>>6);   // 0..799
    float x[24];
    #pragma unroll
    for (int k=0;k<24;k++){
      int c = k*64 + ln;
      x[k] = (c<CH) ? h_cur[c] : ctx[c-CH];
    }
    for (int r=gw; r<CV; r+=800){
      float acc = 0.f;
      if (BF16){
        const u16* w = (const u16*)Wv + (long)r*CH3;
        #pragma unroll
        for (int k=0;k<24;k++){
          u32 u = (u32)w[k*64+ln] << 16;
          acc += __uint_as_float(u)*x[k];
        }
      } else {
        const float* w = (const float*)Wv + (long)r*CH3;
        #pragma unroll
        for (int k=0;k<24;k++) acc += w[k*64+ln]*x[k];
      }
      for (int m=1;m<64;m<<=1) acc += __shfl_xor(acc,m);
      if (ln==0) out[(long)t*CV + r] = acc + lb[r];
    }
    return;
  }

  if (b >= 2){
    // ---- wah = wa @ h_cur for next step (skip at t=0: keeps wa@h_enc) ----
    if (t > 0){
      int j = (b-2)*256 + (tid>>2);
      int cq = (tid&3)*128;
      const float* w = wa + (long)j*CH;
      float acc = 0.f;
      #pragma unroll 4
      for (int k=cq;k<cq+128;k++) acc += w[k]*h_cur[k];
      acc += __shfl_xor(acc,1); acc += __shfl_xor(acc,2);
      if ((tid&3)==0) wah[j] = acc;
    }
    return;
  }

  // ================= coverage (2 WGs x 1024 threads, 256 rows each) =================
  int wg = b;                 // 0..1
  int rp = tid >> 3;          // row-pair 0..127
  int part = tid & 7;         // 8 col-windows x 64 cols
  int r0 = wg*256 + rp*2, r1 = r0 + 1;
  int myrow = (part & 4) ? r1 : r0;
  bool hlane = ((part & 3) == 0);      // part 0 (r0) and part 4 (r1)
  u32 vbase = (u32)(t*CS);
  const float* h_dec = (t==0) ? h_carry : h_cur;

  __shared__ __align__(16) u32 h16[2][320];   // fp16 h ping-pong; phys(w) = w + ((w>>4)<<2)
  __shared__ float al_l[CS];

  if (tid < CS) al_l[tid] = alpha[tid];
  if (tid < 256){
    int w = tid;
    h16[0][w + ((w>>4)<<2)] = packh2(h_dec[2*w], h_dec[2*w+1]);
  }

  // weights: 2 rows x 64-col window -> 32 u32 each
  u32 wreg0[32], wreg1[32];
  {
    const uint4* w0 = (const uint4*)(whc16 + (size_t)r0*CH + part*64);
    const uint4* w1 = (const uint4*)(whc16 + (size_t)r1*CH + part*64);
    #pragma unroll
    for (int k=0;k<8;k++){
      uint4 v = w0[k];
      wreg0[4*k+0]=v.x; wreg0[4*k+1]=v.y; wreg0[4*k+2]=v.z; wreg0[4*k+3]=v.w;
    }
    #pragma unroll
    for (int k=0;k<8;k++){
      uint4 v = w1[k];
      wreg1[4*k+0]=v.x; wreg1[4*k+1]=v.y; wreg1[4*k+2]=v.z; wreg1[4*k+3]=v.w;
    }
  }
  __syncthreads();   // h16[0] + al ready

  // bacc for both rows (fp16 dot over own 64-col window, 8-lane group reduce)
  float bacc;
  {
    float bp0 = 0.f, bp1 = 0.f;
    const uint4* b0 = (const uint4*)(wic16 + (size_t)r0*CH + part*64);
    const uint4* b1 = (const uint4*)(wic16 + (size_t)r1*CH + part*64);
    const uint4* hA = (const uint4*)&h16[0][part*40];
    const uint4* hB = (const uint4*)&h16[0][part*40 + 20];
    #pragma unroll
    for (int k=0;k<8;k++){
      uint4 hv = (k<4) ? hA[k] : hB[k-4];
      uint4 w0 = b0[k], w1 = b1[k];
      bp0 = dot2f(w0.x,hv.x,bp0); bp0 = dot2f(w0.y,hv.y,bp0);
      bp0 = dot2f(w0.z,hv.z,bp0); bp0 = dot2f(w0.w,hv.w,bp0);
      bp1 = dot2f(w1.x,hv.x,bp1); bp1 = dot2f(w1.y,hv.y,bp1);
      bp1 = dot2f(w1.z,hv.z,bp1); bp1 = dot2f(w1.w,hv.w,bp1);
    }
    bool hi = (part & 4);
    float z = hi ? bp1 : bp0;
    float y = hi ? bp0 : bp1;
    z += __shfl_xor(y,4); z += __shfl_xor(z,2); z += __shfl_xor(z,1);
    bacc = z;   // lanes part<4: bacc of r0; part>=4: bacc of r1 (= myrow)
  }
  float bsum = bic[myrow] + bhc[myrow];
  float a_next = 0.f;
  if (hlane){
    cov_vec[myrow] = tanhf(cov_last[myrow]);   // cov_vec position-0 entry
    if (t > 0) h_carry[myrow] = h_dec[myrow];  // commit carry
    a_next = Aenc[myrow];
  }
  __syncthreads();

  int cur = 0;
  for (int s=0;s<CS;s++){
    int nxt = cur^1;
    float a_cur = a_next;
    if (hlane && s < CS-1) a_next = Aenc[(s+1)*CH + myrow];   // prefetch under the dot
    float T = 0.f;
    if (s > 0){
      const uint4* hA = (const uint4*)&h16[cur][part*40];
      const uint4* hB = (const uint4*)&h16[cur][part*40 + 20];
      float acc0 = 0.f, acc1 = 0.f;
      #pragma unroll
      for (int k=0;k<8;k++){
        uint4 hv = (k<4) ? hA[k] : hB[k-4];
        acc0 = dot2f(wreg0[4*k+0], hv.x, acc0);
        acc0 = dot2f(wreg0[4*k+1], hv.y, acc0);
        acc0 = dot2f(wreg0[4*k+2], hv.z, acc0);
        acc0 = dot2f(wreg0[4*k+3], hv.w, acc0);
        acc1 = dot2f(wreg1[4*k+0], hv.x, acc1);
        acc1 = dot2f(wreg1[4*k+1], hv.y, acc1);
        acc1 = dot2f(wreg1[4*k+2], hv.z, acc1);
        acc1 = dot2f(wreg1[4*k+3], hv.w, acc1);
      }
      bool hi = (part & 4);
      float z = hi ? acc1 : acc0;
      float y = hi ? acc0 : acc1;
      z += __shfl_xor(y,4); z += __shfl_xor(z,2); z += __shfl_xor(z,1);
      T = z;     // full dot for myrow, valid on all lanes of the half
    }
    float h = 0.f;
    if (hlane) h = tanhf(T + al_l[s]*(a_cur + bacc) + bsum);
    if (s < CS-1){
      float hpair = __shfl_xor(h, 4);   // lane part0 receives r1's h
      if (part == 0){
        u32 pk = packh2(h, hpair);
        int w = wg*128 + rp;
        h16[nxt][w + ((w>>4)<<2)] = pk;
        u64 pk64 = ((u64)(vbase + (u32)s + 1u) << 32) | (u64)pk;
        __hip_atomic_store(&hc[nxt*256 + w], pk64, __ATOMIC_RELAXED, __HIP_MEMORY_SCOPE_AGENT);
      }
    }
    if (hlane){
      if (s < CS-1) cov_vec[(s+1)*CH + myrow] = tanhf(h);   // fire-and-forget
      else          cov_last[myrow] = h;
    }
    COVBAR();   // B1: own h16[nxt] written (lgkm only; store-ACK not drained)
    if (s < CS-1 && tid >= 896){
      // pollers: waves 14,15 = 128 lanes, 1 foreign word each
      int g = tid - 896;                 // 0..127
      int q = (wg ? 0 : 128) + g;
      u32 want = vbase + (u32)s + 1u;
      const u64* p = &hc[nxt*256 + q];
      u64 x; int gd = 0;
      do {
        x = __hip_atomic_load(p, __ATOMIC_RELAXED, __HIP_MEMORY_SCOPE_AGENT);
      } while ((u32)(x>>32) < want && ++gd < 30000);   // bounded: never hangs
      h16[nxt][q + ((q>>4)<<2)] = (u32)x;
    }
    COVBAR();   // B2: h16[nxt] complete
    cur = nxt;
  }
}

// ---------------- host ----------------
extern "C" void kernel_launch(void* const* d_in, const int* in_sizes, int n_in,
                              void* d_out, int out_size, void* d_ws, size_t ws_size,
                              hipStream_t stream){
  (void)in_sizes; (void)n_in; (void)out_size;
  const int*   iseq = (const int*)d_in[0];
  const int*   oseq = (const int*)d_in[1];
  const float* ee   = (const float*)d_in[2];
  const float* de   = (const float*)d_in[3];
  const float* Wih_f=(const float*)d_in[4];  const float* Whh_f=(const float*)d_in[5];
  const float* bih_f=(const float*)d_in[6];  const float* bhh_f=(const float*)d_in[7];
  const float* Wih_b=(const float*)d_in[8];  const float* Whh_b=(const float*)d_in[9];
  const float* bih_b=(const float*)d_in[10]; const float* bhh_b=(const float*)d_in[11];
  const float* Wih_d=(const float*)d_in[12]; const float* Whh_d=(const float*)d_in[13];
  const float* bih_d=(const float*)d_in[14]; const float* bhh_d=(const float*)d_in[15];
  const float* Wih_c=(const float*)d_in[16]; const float* Whh_c=(const float*)d_in[17];
  const float* bih_c=(const float*)d_in[18]; const float* bhh_c=(const float*)d_in[19];
  const float* va   =(const float*)d_in[20]; const float* wa   =(const float*)d_in[21];
  const float* ua   =(const float*)d_in[22]; const float* vc   =(const float*)d_in[23];
  const float* lin_W=(const float*)d_in[24]; const float* lin_b=(const float*)d_in[25];
  float* out = (float*)d_out;
  char* ws = (char*)d_ws;

  size_t off = 0;
  auto A = [&](size_t bytes){ size_t r = off; off = (off + bytes + 255) & ~(size_t)255; return r; };
  size_t o_whc16 = A((size_t)CH*CH*2);
  size_t o_wic16 = A((size_t)CH*CH*2);
  size_t o_xenc = A((size_t)CS*CE*4), o_xdec = A((size_t)CT*CE*4);
  size_t o_gf   = A((size_t)CS*CH3*4), o_gb  = A((size_t)CS*CH3*4);
  size_t o_of   = A((size_t)CS*CH*4),  o_ob  = A((size_t)CS*CH*4);
  size_t o_uae  = A((size_t)CS*CH*4),  o_Ae  = A((size_t)CS*CH*4);
  size_t o_e    = A(CS*4), o_al = A(CS*4), o_ctx = A(CH2*4);
  size_t o_hc   = A(CH*4), o_hn = A(CH*4), o_cl = A(CH*4);
  size_t o_wah  = A(CH*4);
  size_t o_cv   = A((size_t)CS*CH*4);
  size_t o_hx   = A(2*256*8);
  size_t o_lwb  = A((size_t)CV*CH3*2);
  bool use16 = (off <= ws_size);

  u16* whc16 = (u16*)(ws+o_whc16);    u16* wic16 = (u16*)(ws+o_wic16);
  float* x_enc = (float*)(ws+o_xenc); float* x_dec = (float*)(ws+o_xdec);
  float* gf = (float*)(ws+o_gf);      float* gb = (float*)(ws+o_gb);
  float* outf = (float*)(ws+o_of);    float* outb = (float*)(ws+o_ob);
  float* ua_enc = (float*)(ws+o_uae); float* Aenc = (float*)(ws+o_Ae);
  float* e = (float*)(ws+o_e);        float* alpha = (float*)(ws+o_al);
  float* ctx = (float*)(ws+o_ctx);
  float* h_carry = (float*)(ws+o_hc); float* h_cur = (float*)(ws+o_hn);
  float* cov_last = (float*)(ws+o_cl);
  float* wah = (float*)(ws+o_wah);
  float* cov_vec = (float*)(ws+o_cv);
  u64* hc = (u64*)(ws+o_hx);
  u16* lwb = (u16*)(ws+o_lwb);

  k_init<<<1,256,0,stream>>>((u32*)hc, cov_last);
  k_embed<<<CS,256,0,stream>>>(iseq, oseq, ee, de, x_enc, x_dec);
  k_gi<<<(2*CS*CH3)/256,256,0,stream>>>(Wih_f,bih_f,Wih_b,bih_b,x_enc,gf,gb);
  for (int s=0;s<CS;s++)
    k_enc_step<<<16,256,0,stream>>>(s, Whh_f,bhh_f,Whh_b,bhh_b, gf,gb, outf,outb);
  k_prep2<<<(2*CS*CH+CH)/256,256,0,stream>>>(ua, Wih_c, outf, outb, ua_enc, Aenc, h_carry);
  k_cvt_cov<<<(2*CH*CH)/256,256,0,stream>>>(Whh_c, Wih_c, whc16, wic16);
  if (use16)
    k_cvt<<<2048,256,0,stream>>>(lin_W, lwb, CV*CH3);
  k_wah<<<8,256,0,stream>>>(wa, h_carry, wah);   // initial wah = wa @ h_enc

  for (int t=0;t<CT;t++){
    k_attn<<<CS,256,0,stream>>>(t, vc, va, ua_enc, cov_vec, wah, e);
    k_soft<<<1,128,0,stream>>>(e, outf, outb, alpha, ctx);
    k_gru<<<64,256,0,stream>>>(t, Wih_d,bih_d,Whh_d,bhh_d, ctx, x_dec, h_carry, h_cur);
    if (use16)
      k_tail<1><<<54,1024,0,stream>>>(t, (const void*)lwb, lin_b, h_cur, ctx, out, wa, wah,
                                      whc16, wic16, bih_c, bhh_c, Aenc, alpha,
                                      cov_vec, cov_last, hc, h_carry);
    else
      k_tail<0><<<54,1024,0,stream>>>(t, (const void*)lin_W, lin_b, h_cur, ctx, out, wa, wah,
                                      whc16, wic16, bih_c, bhh_c, Aenc, alpha,
                                      cov_vec, cov_last, hc, h_carry);
  }
}

// Round 11
// 36252.322 us; speedup vs baseline: 1.1094x; 1.1094x over previous
//
#include <hip/hip_runtime.h>
#include <hip/hip_bf16.h>
#include <hip/hip_fp16.h>
#include <math.h>

#define CS 96      // source len
#define CT 96      // target len
#define CE 256     // embed
#define CH 512     // hidden
#define CH2 1024
#define CH3 1536
#define CV 32000
#define CXD 1280   // E + 2H

typedef unsigned int u32;
typedef unsigned short u16;
typedef unsigned long long u64;

__device__ __forceinline__ float sigm(float x){ return 1.f/(1.f+expf(-x)); }

// packed-fp16 dot2 with fp32 accumulate
__device__ __forceinline__ float dot2f(u32 a, u32 b, float c){
#if __has_builtin(__builtin_amdgcn_fdot2)
  typedef _Float16 hv2 __attribute__((ext_vector_type(2)));
  hv2 x = __builtin_bit_cast(hv2, a), y = __builtin_bit_cast(hv2, b);
  return __builtin_amdgcn_fdot2(x, y, c, false);
#else
  __half2 x = __builtin_bit_cast(__half2, a), y = __builtin_bit_cast(__half2, b);
  return c + __half2float(x.x)*__half2float(y.x) + __half2float(x.y)*__half2float(y.y);
#endif
}

__device__ __forceinline__ u32 packh2(float a, float b){
  return (u32)__half_as_ushort(__float2half(a)) | ((u32)__half_as_ushort(__float2half(b)) << 16);
}

__device__ __forceinline__ int idx16(int w){ return w + ((w>>4)<<2); }  // bank-spread phys index

// lgkm-only barrier: drains LDS ops, NOT global stores (keeps store-ACK off the serial path)
#define COVBAR() do{ asm volatile("s_waitcnt lgkmcnt(0)" ::: "memory"); \
                     __builtin_amdgcn_sched_barrier(0); \
                     __builtin_amdgcn_s_barrier(); \
                     __builtin_amdgcn_sched_barrier(0); }while(0)

// ---------------- init: exchange slots + cov_last ----------------
__global__ void k_init(u32* hx, float* cov_last){
  int i = threadIdx.x;
  for (int j = i; j < 1024; j += 256) hx[j] = 0u;   // hc[2][256] u64 -> 1024 u32, tag=0
  for (int j = i; j < CH; j += 256) cov_last[j] = 0.f;
}

// ---------------- embedding gathers ----------------
__global__ void k_embed(const int* iseq, const int* oseq, const float* ee, const float* de,
                        float* x_enc, float* x_dec){
  int s = blockIdx.x, d = threadIdx.x;
  x_enc[s*CE+d] = ee[(long)iseq[s]*CE + d];
  x_dec[s*CE+d] = de[(long)oseq[s]*CE + d];
}

// ---------------- encoder input-gate precompute ----------------
__global__ void k_gi(const float* Wf, const float* bf, const float* Wb, const float* bb,
                     const float* x_enc, float* gf, float* gb){
  int idx = blockIdx.x*256 + threadIdx.x;
  int dir = idx / (CS*CH3);
  int rem = idx - dir*(CS*CH3);
  int s = rem / CH3, r = rem - s*CH3;
  const float* W = dir ? Wb : Wf;
  const float* b = dir ? bb : bf;
  const float* x = x_enc + s*CE;
  const float* w = W + (long)r*CE;
  float acc = b[r];
  #pragma unroll 8
  for (int k=0;k<CE;k++) acc += w[k]*x[k];
  (dir ? gb : gf)[s*CH3 + r] = acc;
}

// ---------------- one encoder step ----------------
__global__ void k_enc_step(int s, const float* Whf, const float* bhf, const float* Whb, const float* bhb,
                           const float* gf, const float* gb, float* outf, float* outb){
  int wg = blockIdx.x;
  int dir = wg >> 3;
  int jb = (wg & 7)*64;
  int t = threadIdx.x;
  int j = jb + (t>>2);
  int c0 = (t&3)*128;
  const float* Whh = dir ? Whb : Whf;
  const float* bhh = dir ? bhb : bhf;
  const float* gi  = dir ? gb : gf;
  float* o = dir ? outb : outf;
  int pos = dir ? (CS-1-s) : s;
  const float* hp = (s>0) ? (o + (dir ? (pos+1)*CH : (s-1)*CH)) : nullptr;
  float ar=0.f, az=0.f, an=0.f;
  if (s > 0){
    const float* wr = Whh + (long)j*CH;
    const float* wz = Whh + (long)(j+CH)*CH;
    const float* wn = Whh + (long)(j+2*CH)*CH;
    #pragma unroll 4
    for (int k=c0;k<c0+128;k++){
      float h = hp[k];
      ar += wr[k]*h; az += wz[k]*h; an += wn[k]*h;
    }
  }
  ar += __shfl_xor(ar,1); ar += __shfl_xor(ar,2);
  az += __shfl_xor(az,1); az += __shfl_xor(az,2);
  an += __shfl_xor(an,1); an += __shfl_xor(an,2);
  if ((t&3)==0){
    const float* g = gi + pos*CH3;
    float hpj = (s>0) ? hp[j] : 0.f;
    float r = sigm(g[j]       + ar + bhh[j]);
    float z = sigm(g[j+CH]    + az + bhh[j+CH]);
    float n = tanhf(g[j+2*CH] + r*(an + bhh[j+2*CH]));
    o[pos*CH + j] = (1.f-z)*n + z*hpj;
  }
}

// ---------------- ua_enc / Aenc precompute + h_carry init ----------------
__global__ void k_prep2(const float* ua, const float* Wic, const float* outf, const float* outb,
                        float* ua_enc, float* Aenc, float* h_carry){
  int idx = blockIdx.x*256 + threadIdx.x;
  if (idx < 2*CS*CH){
    int which = idx / (CS*CH);
    int rem = idx - which*(CS*CH);
    int s = rem / CH, r = rem - s*CH;
    const float* of = outf + s*CH;
    const float* ob = outb + s*CH;
    const float* w = which ? (Wic + (long)r*CH3) : (ua + (long)r*CH2);
    float acc = 0.f;
    #pragma unroll 4
    for (int k=0;k<CH;k++) acc += w[k]*of[k];
    #pragma unroll 4
    for (int k=0;k<CH;k++) acc += w[CH+k]*ob[k];
    (which ? Aenc : ua_enc)[s*CH + r] = acc;
  } else if (idx < 2*CS*CH + CH){
    int j = idx - 2*CS*CH;
    h_carry[j] = outf[(CS-1)*CH + j];
  }
}

// ---------------- fp32 -> bf16 (RNE) for lin_W ----------------
__global__ void k_cvt(const float* w, u16* o, int n){
  int i = blockIdx.x*blockDim.x + threadIdx.x;
  int stride = gridDim.x*blockDim.x;
  for (; i<n; i+=stride){
    union { float f; u32 u; } v; v.f = w[i];
    u32 r = (v.u + 0x7fffu + ((v.u>>16)&1u)) >> 16;
    o[i] = (u16)r;
  }
}

// ---------------- fp32 -> fp16 for coverage weights ----------------
__global__ void k_cvt_cov(const float* Whc, const float* Wic, u16* whc16, u16* wic16){
  int i = blockIdx.x*256 + threadIdx.x;     // 0 .. 2*CH*CH
  if (i < CH*CH){
    whc16[i] = __half_as_ushort(__float2half(Whc[i]));
  } else {
    int j = i - CH*CH;
    int r = j >> 9, c = j & 511;
    wic16[j] = __half_as_ushort(__float2half(Wic[(long)r*CH3 + CH2 + c]));
  }
}

// ---------------- wah = wa @ h (pre-loop only) ----------------
__global__ void k_wah(const float* wa, const float* h, float* wah){
  int j = blockIdx.x*64 + (threadIdx.x>>2);
  int c0 = (threadIdx.x&3)*128;
  const float* w = wa + (long)j*CH;
  float acc = 0.f;
  #pragma unroll 4
  for (int k=c0;k<c0+128;k++) acc += w[k]*h[k];
  acc += __shfl_xor(acc,1); acc += __shfl_xor(acc,2);
  if ((threadIdx.x&3)==0) wah[j] = acc;
}

// ---------------- attention scores e[s] ----------------
__global__ void k_attn(int t, const float* vc, const float* va,
                       const float* ua_enc, const float* cov_vec, const float* wah, float* e){
  int s = blockIdx.x, tid = threadIdx.x;
  __shared__ float red[4];
  float sum = 0.f;
  #pragma unroll
  for (int jj=0;jj<2;jj++){
    int j = tid + jj*256;
    float acc = ua_enc[s*CH + j] + wah[j];
    if (t > 0){
      const float* v = vc + (long)j*CH;
      const float* cvs = cov_vec + s*CH;
      #pragma unroll 4
      for (int k=0;k<CH;k++) acc += v[k]*cvs[k];
    }
    sum += va[j]*tanhf(acc);
  }
  for (int m=1;m<64;m<<=1) sum += __shfl_xor(sum,m);
  if ((tid&63)==0) red[tid>>6] = sum;
  __syncthreads();
  if (tid==0) e[s] = red[0]+red[1]+red[2]+red[3];
}

// ---------------- softmax + context ----------------
__global__ void k_soft(const float* e, const float* outf, const float* outb, float* alpha, float* ctx){
  int tid = threadIdx.x; // 128
  __shared__ float al[CS];
  __shared__ float rmax[2], rsum[2];
  float v = (tid<CS) ? e[tid] : -1e30f;
  float m = v;
  for (int k=1;k<64;k<<=1) m = fmaxf(m, __shfl_xor(m,k));
  if ((tid&63)==0) rmax[tid>>6] = m;
  __syncthreads();
  float gm = fmaxf(rmax[0], rmax[1]);
  float ex = (tid<CS) ? expf(v-gm) : 0.f;
  float sm2 = ex;
  for (int k=1;k<64;k<<=1) sm2 += __shfl_xor(sm2,k);
  if ((tid&63)==0) rsum[tid>>6] = sm2;
  __syncthreads();
  float inv = 1.f/(rsum[0]+rsum[1]);
  if (tid<CS){ float a = ex*inv; al[tid] = a; alpha[tid] = a; }
  __syncthreads();
  #pragma unroll
  for (int k=0;k<8;k++){
    int d = k*128 + tid;
    const float* src = (d<CH) ? outf : outb;
    int dd = (d<CH) ? d : d-CH;
    float acc = 0.f;
    for (int s2=0;s2<CS;s2++) acc += al[s2]*src[s2*CH+dd];
    ctx[d] = acc;
  }
}

// ---------------- decoder GRU ----------------
__global__ void k_gru(int t, const float* Wi, const float* bi, const float* Wh, const float* bh,
                      const float* ctx, const float* x_dec, const float* h_carry, float* h_cur){
  int wg = blockIdx.x, tid = threadIdx.x;
  int j = wg*8 + (tid>>5);
  int ln = tid&31;
  const float* xd = x_dec + t*CE;
  float ar=0.f, az=0.f, an=0.f;
  {
    int c0 = ln*40;
    const float* wr = Wi + (long)j*CXD;
    const float* wz = Wi + (long)(j+CH)*CXD;
    const float* wn = Wi + (long)(j+2*CH)*CXD;
    for (int k=c0;k<c0+40;k++){
      float x = (k<CH2) ? ctx[k] : xd[k-CH2];
      ar += wr[k]*x; az += wz[k]*x; an += wn[k]*x;
    }
  }
  float hr=0.f, hz=0.f, hn2=0.f;
  {
    int c0 = ln*16;
    const float* wr = Wh + (long)j*CH;
    const float* wz = Wh + (long)(j+CH)*CH;
    const float* wn = Wh + (long)(j+2*CH)*CH;
    for (int k=c0;k<c0+16;k++){
      float hv = h_carry[k];
      hr += wr[k]*hv; hz += wz[k]*hv; hn2 += wn[k]*hv;
    }
  }
  for (int m=1;m<32;m<<=1){
    ar+=__shfl_xor(ar,m); az+=__shfl_xor(az,m); an+=__shfl_xor(an,m);
    hr+=__shfl_xor(hr,m); hz+=__shfl_xor(hz,m); hn2+=__shfl_xor(hn2,m);
  }
  if (ln==0){
    float hprev = h_carry[j];
    float r = sigm(ar + bi[j]       + hr + bh[j]);
    float z = sigm(az + bi[j+CH]    + hz + bh[j+CH]);
    float n = tanhf(an + bi[j+2*CH] + r*(hn2 + bh[j+2*CH]));
    h_cur[j] = (1.f-z)*n + z*hprev;
  }
}

// ---------------- fused tail: blocks 0..3 coverage | 4..5 wah | 6..55 logits ----------------
// cov: producer/poller wave specialization.  Waves 0-7 compute (1 row x 128-col window per
// thread); waves 8-10 poll CONTINUOUSLY from barrier-exit (overlapping peers' compute+RTT);
// ONE lgkm-only barrier per position.  Single-barrier safety: position s reads h16[cur],
// writes h16[nxt] (producers: own words; pollers: foreign words — disjoint).  Writes to
// h16[cur] happen only at position s+1, i.e. after the barrier that follows s's reads.
template<int BF16>
__launch_bounds__(1024)
__global__ void k_tail(int t, const void* Wv, const float* lb, const float* h_cur, const float* ctx,
                       float* out, const float* wa, float* wah,
                       const u16* whc16, const u16* wic16, const float* bic, const float* bhc,
                       const float* Aenc, const float* alpha,
                       float* cov_vec, float* cov_last, u64* hc, float* h_carry){
  int b = blockIdx.x, tid = threadIdx.x;

  if (b >= 6){
    // ---- logits: 50 blocks x 16 waves = 800 row-walkers ----
    int ln = tid&63;
    int gw = (b-6)*16 + (tid>>6);   // 0..799
    float x[24];
    #pragma unroll
    for (int k=0;k<24;k++){
      int c = k*64 + ln;
      x[k] = (c<CH) ? h_cur[c] : ctx[c-CH];
    }
    for (int r=gw; r<CV; r+=800){
      float acc = 0.f;
      if (BF16){
        const u16* w = (const u16*)Wv + (long)r*CH3;
        #pragma unroll
        for (int k=0;k<24;k++){
          u32 u = (u32)w[k*64+ln] << 16;
          acc += __uint_as_float(u)*x[k];
        }
      } else {
        const float* w = (const float*)Wv + (long)r*CH3;
        #pragma unroll
        for (int k=0;k<24;k++) acc += w[k*64+ln]*x[k];
      }
      for (int m=1;m<64;m<<=1) acc += __shfl_xor(acc,m);
      if (ln==0) out[(long)t*CV + r] = acc + lb[r];
    }
    return;
  }

  if (b >= 4){
    // ---- wah = wa @ h_cur for next step (skip at t=0: keeps wa@h_enc) ----
    if (t > 0){
      int j = (b-4)*256 + (tid>>2);
      int cq = (tid&3)*128;
      const float* w = wa + (long)j*CH;
      float acc = 0.f;
      #pragma unroll 4
      for (int k=cq;k<cq+128;k++) acc += w[k]*h_cur[k];
      acc += __shfl_xor(acc,1); acc += __shfl_xor(acc,2);
      if ((tid&3)==0) wah[j] = acc;
    }
    return;
  }

  // ================= coverage (4 WGs x 1024; waves 0-7 compute, 8-10 poll) =================
  int wg = b;               // 0..3
  u32 vbase = (u32)(t*CS);
  const float* h_dec = (t==0) ? h_carry : h_cur;

  __shared__ __align__(16) u32 h16[2][320];   // fp16 h ping-pong; phys = idx16(w)
  __shared__ float al_l[CS];

  if (tid < CS) al_l[tid] = alpha[tid];
  if (tid < 256) h16[0][idx16(tid)] = packh2(h_dec[2*tid], h_dec[2*tid+1]);

  // ---- compute-thread prologue (tid < 512) ----
  int q = tid & 3;           // 128-col window
  int lr = tid >> 2;         // local row 0..127
  int row = wg*128 + lr;
  bool hlane = (q == 0);
  u32 wreg[64];
  float bacc = 0.f, bsum = 0.f, a_next = 0.f;
  if (tid < 512){
    const uint4* wp = (const uint4*)(whc16 + (size_t)row*CH + q*128);
    #pragma unroll
    for (int k=0;k<16;k++){
      uint4 v = wp[k];
      wreg[4*k+0]=v.x; wreg[4*k+1]=v.y; wreg[4*k+2]=v.z; wreg[4*k+3]=v.w;
      if ((k&3)==3) asm volatile("" ::: "memory");   // cap in-flight loads (spill guard)
    }
  }
  __syncthreads();   // h16[0] + al ready

  if (tid < 512){
    // bacc = Wih_c[row,1024+q*128 : +128] @ h_dec window (fp16), reduce over quad
    const uint4* bw = (const uint4*)(wic16 + (size_t)row*CH + q*128);
    #pragma unroll
    for (int k=0;k<16;k++){
      uint4 wv = bw[k];
      const uint4 hv = *(const uint4*)&h16[0][idx16(q*64 + 4*k)];
      bacc = dot2f(wv.x,hv.x,bacc); bacc = dot2f(wv.y,hv.y,bacc);
      bacc = dot2f(wv.z,hv.z,bacc); bacc = dot2f(wv.w,hv.w,bacc);
    }
    bacc += __shfl_xor(bacc,1); bacc += __shfl_xor(bacc,2);   // full on all 4 lanes
    bsum = bic[row] + bhc[row];
    if (hlane){
      cov_vec[row] = tanhf(cov_last[row]);       // cov_vec position-0 entry
      if (t > 0) h_carry[row] = h_dec[row];      // commit carry
      a_next = Aenc[row];
    }
  }

  int g = tid - 512;                              // poller id 0..191 (waves 8-10)
  int qf = (g >= 0 && g < 192) ? (g + ((g >= wg*64) ? 64 : 0)) : 0;

  int cur = 0;
  for (int s=0;s<CS;s++){
    int nxt = cur^1;
    if (tid < 512){
      float a_cur = a_next;
      if (hlane && s < CS-1) a_next = Aenc[(s+1)*CH + row];   // prefetch under the dot
      float T = 0.f;
      if (s > 0){
        float acc = 0.f;
        const u32* hb = &h16[cur][0];
        #pragma unroll
        for (int k=0;k<16;k++){
          const uint4 hv = *(const uint4*)&hb[idx16(q*64 + 4*k)];
          acc = dot2f(wreg[4*k+0], hv.x, acc);
          acc = dot2f(wreg[4*k+1], hv.y, acc);
          acc = dot2f(wreg[4*k+2], hv.z, acc);
          acc = dot2f(wreg[4*k+3], hv.w, acc);
        }
        acc += __shfl_xor(acc,1); acc += __shfl_xor(acc,2);   // full row dot, all 4 lanes
        T = acc;
      }
      float h = 0.f;
      if (hlane) h = tanhf(T + al_l[s]*(a_cur + bacc) + bsum);
      if (s < CS-1){
        float hpair = __shfl_xor(h, 4);          // rows 2k <-> 2k+1 (lanes 8k, 8k+4)
        if ((tid & 7) == 0){
          u32 pk = packh2(h, hpair);
          int w = wg*64 + (tid>>3);
          h16[nxt][idx16(w)] = pk;
          u64 pk64 = ((u64)(vbase + (u32)s + 1u) << 32) | (u64)pk;
          __hip_atomic_store(&hc[nxt*256 + w], pk64, __ATOMIC_RELAXED, __HIP_MEMORY_SCOPE_AGENT);
        }
      }
      if (hlane){
        if (s < CS-1) cov_vec[(s+1)*CH + row] = tanhf(h);     // fire-and-forget
        else          cov_last[row] = h;
      }
    } else if (g < 192 && s < CS-1){
      // dedicated pollers: start at barrier-exit, overlap peers' compute + RTT
      u32 want = vbase + (u32)s + 1u;
      const u64* p = &hc[nxt*256 + qf];
      u64 x; int gd = 0;
      do {
        x = __hip_atomic_load(p, __ATOMIC_RELAXED, __HIP_MEMORY_SCOPE_AGENT);
      } while ((u32)(x>>32) < want && ++gd < 30000);   // bounded: never hangs
      h16[nxt][idx16(qf)] = (u32)x;
    }
    COVBAR();   // single barrier per position (lgkm-only; global store-ACK not drained)
    cur = nxt;
  }
}

// ---------------- host ----------------
extern "C" void kernel_launch(void* const* d_in, const int* in_sizes, int n_in,
                              void* d_out, int out_size, void* d_ws, size_t ws_size,
                              hipStream_t stream){
  (void)in_sizes; (void)n_in; (void)out_size;
  const int*   iseq = (const int*)d_in[0];
  const int*   oseq = (const int*)d_in[1];
  const float* ee   = (const float*)d_in[2];
  const float* de   = (const float*)d_in[3];
  const float* Wih_f=(const float*)d_in[4];  const float* Whh_f=(const float*)d_in[5];
  const float* bih_f=(const float*)d_in[6];  const float* bhh_f=(const float*)d_in[7];
  const float* Wih_b=(const float*)d_in[8];  const float* Whh_b=(const float*)d_in[9];
  const float* bih_b=(const float*)d_in[10]; const float* bhh_b=(const float*)d_in[11];
  const float* Wih_d=(const float*)d_in[12]; const float* Whh_d=(const float*)d_in[13];
  const float* bih_d=(const float*)d_in[14]; const float* bhh_d=(const float*)d_in[15];
  const float* Wih_c=(const float*)d_in[16]; const float* Whh_c=(const float*)d_in[17];
  const float* bih_c=(const float*)d_in[18]; const float* bhh_c=(const float*)d_in[19];
  const float* va   =(const float*)d_in[20]; const float* wa   =(const float*)d_in[21];
  const float* ua   =(const float*)d_in[22]; const float* vc   =(const float*)d_in[23];
  const float* lin_W=(const float*)d_in[24]; const float* lin_b=(const float*)d_in[25];
  float* out = (float*)d_out;
  char* ws = (char*)d_ws;

  size_t off = 0;
  auto A = [&](size_t bytes){ size_t r = off; off = (off + bytes + 255) & ~(size_t)255; return r; };
  size_t o_whc16 = A((size_t)CH*CH*2);
  size_t o_wic16 = A((size_t)CH*CH*2);
  size_t o_xenc = A((size_t)CS*CE*4), o_xdec = A((size_t)CT*CE*4);
  size_t o_gf   = A((size_t)CS*CH3*4), o_gb  = A((size_t)CS*CH3*4);
  size_t o_of   = A((size_t)CS*CH*4),  o_ob  = A((size_t)CS*CH*4);
  size_t o_uae  = A((size_t)CS*CH*4),  o_Ae  = A((size_t)CS*CH*4);
  size_t o_e    = A(CS*4), o_al = A(CS*4), o_ctx = A(CH2*4);
  size_t o_hc   = A(CH*4), o_hn = A(CH*4), o_cl = A(CH*4);
  size_t o_wah  = A(CH*4);
  size_t o_cv   = A((size_t)CS*CH*4);
  size_t o_hx   = A(2*256*8);
  size_t o_lwb  = A((size_t)CV*CH3*2);
  bool use16 = (off <= ws_size);

  u16* whc16 = (u16*)(ws+o_whc16);    u16* wic16 = (u16*)(ws+o_wic16);
  float* x_enc = (float*)(ws+o_xenc); float* x_dec = (float*)(ws+o_xdec);
  float* gf = (float*)(ws+o_gf);      float* gb = (float*)(ws+o_gb);
  float* outf = (float*)(ws+o_of);    float* outb = (float*)(ws+o_ob);
  float* ua_enc = (float*)(ws+o_uae); float* Aenc = (float*)(ws+o_Ae);
  float* e = (float*)(ws+o_e);        float* alpha = (float*)(ws+o_al);
  float* ctx = (float*)(ws+o_ctx);
  float* h_carry = (float*)(ws+o_hc); float* h_cur = (float*)(ws+o_hn);
  float* cov_last = (float*)(ws+o_cl);
  float* wah = (float*)(ws+o_wah);
  float* cov_vec = (float*)(ws+o_cv);
  u64* hc = (u64*)(ws+o_hx);
  u16* lwb = (u16*)(ws+o_lwb);

  k_init<<<1,256,0,stream>>>((u32*)hc, cov_last);
  k_embed<<<CS,256,0,stream>>>(iseq, oseq, ee, de, x_enc, x_dec);
  k_gi<<<(2*CS*CH3)/256,256,0,stream>>>(Wih_f,bih_f,Wih_b,bih_b,x_enc,gf,gb);
  for (int s=0;s<CS;s++)
    k_enc_step<<<16,256,0,stream>>>(s, Whh_f,bhh_f,Whh_b,bhh_b, gf,gb, outf,outb);
  k_prep2<<<(2*CS*CH+CH)/256,256,0,stream>>>(ua, Wih_c, outf, outb, ua_enc, Aenc, h_carry);
  k_cvt_cov<<<(2*CH*CH)/256,256,0,stream>>>(Whh_c, Wih_c, whc16, wic16);
  if (use16)
    k_cvt<<<2048,256,0,stream>>>(lin_W, lwb, CV*CH3);
  k_wah<<<8,256,0,stream>>>(wa, h_carry, wah);   // initial wah = wa @ h_enc

  for (int t=0;t<CT;t++){
    k_attn<<<CS,256,0,stream>>>(t, vc, va, ua_enc, cov_vec, wah, e);
    k_soft<<<1,128,0,stream>>>(e, outf, outb, alpha, ctx);
    k_gru<<<64,256,0,stream>>>(t, Wih_d,bih_d,Whh_d,bhh_d, ctx, x_dec, h_carry, h_cur);
    if (use16)
      k_tail<1><<<56,1024,0,stream>>>(t, (const void*)lwb, lin_b, h_cur, ctx, out, wa, wah,
                                      whc16, wic16, bih_c, bhh_c, Aenc, alpha,
                                      cov_vec, cov_last, hc, h_carry);
    else
      k_tail<0><<<56,1024,0,stream>>>(t, (const void*)lin_W, lin_b, h_cur, ctx, out, wa, wah,
                                      whc16, wic16, bih_c, bhh_c, Aenc, alpha,
                                      cov_vec, cov_last, hc, h_carry);
  }
}